// Round 6
// baseline (66.656 us; speedup 1.0000x reference)
//
#include <hip/hip_runtime.h>
#include <stdint.h>

#define BATCH 16
#define NPTS 4096
#define DIM 384
#define NTOK (2*NPTS)
#define F4PT (DIM/4)   // 96 float4 groups per token

typedef unsigned long long u64;

// Morton spread: place bit b of an 8-bit value at position 3b.
__device__ __forceinline__ uint32_t spread3(uint32_t x) {
    x = (x | (x << 8)) & 0x00F00Fu;
    x = (x | (x << 4)) & 0x0C30C3u;
    x = (x | (x << 2)) & 0x249249u;
    return x;
}

// Exact port of the reference Skilling transform (bits=8, ndim=3).
__device__ __forceinline__ uint32_t hilbert3(uint32_t x0, uint32_t x1, uint32_t x2) {
    #pragma unroll
    for (uint32_t q = 128; q > 1; q >>= 1) {
        uint32_t pm = q - 1;
        if (x0 & q) x0 ^= pm;
        uint32_t t = (x0 ^ x1) & pm;
        if (x1 & q) { x0 ^= pm; } else { x0 ^= t; x1 ^= t; }
        t = (x0 ^ x2) & pm;
        if (x2 & q) { x0 ^= pm; } else { x0 ^= t; x2 ^= t; }
    }
    x1 ^= x0;
    x2 ^= x1;
    uint32_t t = 0;
    #pragma unroll
    for (uint32_t q = 128; q > 1; q >>= 1) { if (x2 & q) t ^= (q - 1); }
    x0 ^= t; x1 ^= t; x2 ^= t;
    return (spread3(x0) << 2) | (spread3(x1) << 1) | spread3(x2);
}

// One block per (batch, variant): minmax -> quantize -> hilbert -> stable LSD
// radix sort (4 passes x 6-bit digit over the 24-bit code) -> scatter order.
// Element i = w*256 + r*64 + lane; (wave, r, lane) order == element order, so
// ballot ranking + slot-ordered histograms make each pass stable.
__global__ __launch_bounds__(1024) void order_radix_kernel(const float* __restrict__ x,
                                                           int* __restrict__ order) {
    const int b = blockIdx.x >> 1;
    const int v = blockIdx.x & 1;
    const int t = threadIdx.x;
    const int lane = t & 63;
    const int w = t >> 6;

    __shared__ uint32_t scode[NPTS];          // 16 KB
    __shared__ unsigned short sidx[NPTS];     // 8 KB
    __shared__ uint32_t hist[64 * 64];        // hist[d*64 + (w*4+r)], 16 KB
    __shared__ uint32_t totals[64];
    __shared__ uint32_t baseArr[64];
    __shared__ float red[16 * 6];

    const float* xb = x + (size_t)b * NPTS * 3;

    // Load this thread's 4 elements (i = w*256 + r*64 + lane).
    float px[4], py[4], pz[4];
    #pragma unroll
    for (int r = 0; r < 4; ++r) {
        int i = (w << 8) + (r << 6) + lane;
        px[r] = xb[3*i+0]; py[r] = xb[3*i+1]; pz[r] = xb[3*i+2];
    }

    // Per-batch min/max reduction.
    float mnx = 1e30f, mny = 1e30f, mnz = 1e30f;
    float mxx = -1e30f, mxy = -1e30f, mxz = -1e30f;
    #pragma unroll
    for (int r = 0; r < 4; ++r) {
        mnx = fminf(mnx, px[r]); mxx = fmaxf(mxx, px[r]);
        mny = fminf(mny, py[r]); mxy = fmaxf(mxy, py[r]);
        mnz = fminf(mnz, pz[r]); mxz = fmaxf(mxz, pz[r]);
    }
    #pragma unroll
    for (int off = 32; off > 0; off >>= 1) {
        mnx = fminf(mnx, __shfl_xor(mnx, off));
        mny = fminf(mny, __shfl_xor(mny, off));
        mnz = fminf(mnz, __shfl_xor(mnz, off));
        mxx = fmaxf(mxx, __shfl_xor(mxx, off));
        mxy = fmaxf(mxy, __shfl_xor(mxy, off));
        mxz = fmaxf(mxz, __shfl_xor(mxz, off));
    }
    if (lane == 0) {
        red[w*6+0] = mnx; red[w*6+1] = mny; red[w*6+2] = mnz;
        red[w*6+3] = mxx; red[w*6+4] = mxy; red[w*6+5] = mxz;
    }
    // Clear hist while the reduction settles (hist untouched so far).
    #pragma unroll
    for (int c = 0; c < 4; ++c) hist[t + c * 1024] = 0u;
    __syncthreads();
    if (t == 0) {
        for (int ww = 1; ww < 16; ++ww) {
            mnx = fminf(mnx, red[ww*6+0]); mny = fminf(mny, red[ww*6+1]);
            mnz = fminf(mnz, red[ww*6+2]); mxx = fmaxf(mxx, red[ww*6+3]);
            mxy = fmaxf(mxy, red[ww*6+4]); mxz = fmaxf(mxz, red[ww*6+5]);
        }
        red[0] = mnx; red[1] = mny; red[2] = mnz;
        red[3] = fmaxf(mxx - mnx, 1e-6f);
        red[4] = fmaxf(mxy - mny, 1e-6f);
        red[5] = fmaxf(mxz - mnz, 1e-6f);
    }
    __syncthreads();
    mnx = red[0]; mny = red[1]; mnz = red[2];
    const float spx = red[3], spy = red[4], spz = red[5];

    // Codes (24-bit) + idx payload.
    uint32_t code[4];
    unsigned short myidx[4];
    #pragma unroll
    for (int r = 0; r < 4; ++r) {
        int i = (w << 8) + (r << 6) + lane;
        float gx = fminf(fmaxf(((px[r] - mnx) / spx) * 255.0f, 0.0f), 255.0f);
        float gy = fminf(fmaxf(((py[r] - mny) / spy) * 255.0f, 0.0f), 255.0f);
        float gz = fminf(fmaxf(((pz[r] - mnz) / spz) * 255.0f, 0.0f), 255.0f);
        uint32_t ix = (uint32_t)(int)gx;
        uint32_t iy = (uint32_t)(int)gy;
        uint32_t iz = (uint32_t)(int)gz;
        uint32_t a0 = v ? iz : ix;
        uint32_t a2 = v ? ix : iz;
        code[r] = hilbert3(a0, iy, a2);
        myidx[r] = (unsigned short)i;
    }

    const u64 below_mask = (1ull << lane) - 1ull;
    int* ob = order + (((b << 1) | v) << 12);

    // 4 stable radix passes, 6-bit digits over code bits [0,24).
    #pragma unroll
    for (int p = 0; p < 4; ++p) {
        const int sh = 6 * p;

        // Rank within (wave, r) slot via ballot match.
        unsigned dd[4], rk[4];
        #pragma unroll
        for (int r = 0; r < 4; ++r) {
            unsigned d = (code[r] >> sh) & 63u;
            u64 m = ~0ull;
            #pragma unroll
            for (int bit = 0; bit < 6; ++bit) {
                u64 bal = __ballot((int)((d >> bit) & 1u));
                m &= ((d >> bit) & 1u) ? bal : ~bal;
            }
            unsigned rkr = (unsigned)__popcll(m & below_mask);
            dd[r] = d; rk[r] = rkr;
            if (rkr == 0u) hist[d * 64 + (w << 2) + r] = (unsigned)__popcll(m);
        }
        __syncthreads();

        // Wave w scans bins 4w..4w+3 (exclusive over 64 slots each).
        #pragma unroll
        for (int bb = 0; bb < 4; ++bb) {
            int bin = (w << 2) + bb;
            unsigned val = hist[bin * 64 + lane];
            unsigned orig = val;
            #pragma unroll
            for (int off = 1; off < 64; off <<= 1) {
                unsigned nv = __shfl_up(val, off);
                if (lane >= off) val += nv;
            }
            hist[bin * 64 + lane] = val - orig;
            if (lane == 63) totals[bin] = val;
        }
        __syncthreads();

        // Exclusive scan of 64 bin totals (one wave, one lane per bin).
        if (w == 0) {
            unsigned tv = totals[lane];
            unsigned orig = tv;
            #pragma unroll
            for (int off = 1; off < 64; off <<= 1) {
                unsigned nv = __shfl_up(tv, off);
                if (lane >= off) tv += nv;
            }
            baseArr[lane] = tv - orig;
        }
        __syncthreads();

        unsigned pos[4];
        #pragma unroll
        for (int r = 0; r < 4; ++r)
            pos[r] = baseArr[dd[r]] + hist[dd[r] * 64 + (w << 2) + r] + rk[r];

        if (p < 3) {
            // Stable scatter through LDS, gather back, re-clear hist.
            #pragma unroll
            for (int r = 0; r < 4; ++r) {
                scode[pos[r]] = code[r];
                sidx[pos[r]] = myidx[r];
            }
            __syncthreads();
            #pragma unroll
            for (int r = 0; r < 4; ++r) {
                int i = (w << 8) + (r << 6) + lane;
                code[r] = scode[i];
                myidx[r] = sidx[i];
            }
            #pragma unroll
            for (int c = 0; c < 4; ++c) hist[t + c * 1024] = 0u;
            __syncthreads();
        } else {
            // Final pass: scatter indices straight to global.
            #pragma unroll
            for (int r = 0; r < 4; ++r)
                ob[pos[r]] = (int)myidx[r];
        }
    }
}

// Grid-stride over float4 output groups. Coeffs staged in LDS.
__global__ __launch_bounds__(256) void token_kernel(const float* __restrict__ x,
                                                    const float* __restrict__ W,
                                                    const float* __restrict__ bias,
                                                    const float* __restrict__ gamma,
                                                    const float* __restrict__ beta,
                                                    const int* __restrict__ order,
                                                    float* __restrict__ out) {
    __shared__ __align__(16) float sW0[2][DIM];
    __shared__ __align__(16) float sW1[2][DIM];
    __shared__ __align__(16) float sW2[2][DIM];
    __shared__ __align__(16) float sC[2][DIM];
    for (int i = threadIdx.x; i < 2 * DIM; i += 256) {
        int v = i / DIM;
        int d = i - v * DIM;
        float g = gamma[i];
        sW0[v][d] = g * W[d*3+0];
        sW1[v][d] = g * W[d*3+1];
        sW2[v][d] = g * W[d*3+2];
        sC[v][d]  = g * bias[d] + beta[i];
    }
    __syncthreads();

    const int total = BATCH * NTOK * F4PT;   // 12,582,912
    const int stride = gridDim.x * blockDim.x;
    for (int g4 = blockIdx.x * blockDim.x + threadIdx.x; g4 < total; g4 += stride) {
        int token = g4 / F4PT;
        int grp = g4 - token * F4PT;
        int b = token >> 13;           // / NTOK
        int nn = token & (NTOK - 1);
        int v = nn >> 12;              // / NPTS
        int n = nn & (NPTS - 1);
        int idx = order[(((b << 1) | v) << 12) + n];
        const float* p = x + (size_t)(b * NPTS + idx) * 3;
        float px = p[0], py = p[1], pz = p[2];
        int d0 = grp << 2;
        float4 w0 = *(const float4*)&sW0[v][d0];
        float4 w1 = *(const float4*)&sW1[v][d0];
        float4 w2 = *(const float4*)&sW2[v][d0];
        float4 c  = *(const float4*)&sC[v][d0];
        float4 o;
        o.x = px*w0.x + py*w1.x + pz*w2.x + c.x;
        o.y = px*w0.y + py*w1.y + pz*w2.y + c.y;
        o.z = px*w0.z + py*w1.z + pz*w2.z + c.z;
        o.w = px*w0.w + py*w1.w + pz*w2.w + c.w;
        reinterpret_cast<float4*>(out)[g4] = o;
    }
}

extern "C" void kernel_launch(void* const* d_in, const int* in_sizes, int n_in,
                              void* d_out, int out_size, void* d_ws, size_t ws_size,
                              hipStream_t stream) {
    const float* x     = (const float*)d_in[0];
    const float* W     = (const float*)d_in[1];
    const float* bias  = (const float*)d_in[2];
    const float* gamma = (const float*)d_in[3];
    const float* beta  = (const float*)d_in[4];

    int* order = (int*)d_ws;   // 16*2*4096 int32 = 512 KB

    hipLaunchKernelGGL(order_radix_kernel, dim3(BATCH * 2), dim3(1024), 0, stream, x, order);
    hipLaunchKernelGGL(token_kernel,       dim3(2048),      dim3(256),  0, stream,
                       x, W, bias, gamma, beta, order, (float*)d_out);
}

// Round 7
// 64.079 us; speedup vs baseline: 1.0402x; 1.0402x over previous
//
#include <hip/hip_runtime.h>
#include <stdint.h>

#define BATCH 16
#define NPTS 4096
#define DIM 384
#define NTOK (2*NPTS)
#define F4PT (DIM/4)   // 96 float4 groups per token

typedef unsigned long long u64;

// Morton spread: place bit b of an 8-bit value at position 3b.
__device__ __forceinline__ uint32_t spread3(uint32_t x) {
    x = (x | (x << 8)) & 0x00F00Fu;
    x = (x | (x << 4)) & 0x0C30C3u;
    x = (x | (x << 2)) & 0x249249u;
    return x;
}

// Exact port of the reference Skilling transform (bits=8, ndim=3).
__device__ __forceinline__ uint32_t hilbert3(uint32_t x0, uint32_t x1, uint32_t x2) {
    #pragma unroll
    for (uint32_t q = 128; q > 1; q >>= 1) {
        uint32_t pm = q - 1;
        if (x0 & q) x0 ^= pm;
        uint32_t t = (x0 ^ x1) & pm;
        if (x1 & q) { x0 ^= pm; } else { x0 ^= t; x1 ^= t; }
        t = (x0 ^ x2) & pm;
        if (x2 & q) { x0 ^= pm; } else { x0 ^= t; x2 ^= t; }
    }
    x1 ^= x0;
    x2 ^= x1;
    uint32_t t = 0;
    #pragma unroll
    for (uint32_t q = 128; q > 1; q >>= 1) { if (x2 & q) t ^= (q - 1); }
    x0 ^= t; x1 ^= t; x2 ^= t;
    return (spread3(x0) << 2) | (spread3(x1) << 1) | spread3(x2);
}

// One block per (batch, variant): minmax -> quantize -> hilbert -> stable LSD
// radix sort (6 passes x 4-bit digit over the 24-bit code) -> scatter order.
// Element i = w*256 + r*64 + lane; (wave, r, lane) order == element order, so
// ballot ranking + slot-ordered histograms make each pass stable.
// Barrier schedule per pass: B1 after rank (hist slot counts + atomic binTot),
// B2 after scans (slot-prefix + base-prefix), B3 after LDS scatter,
// B4 after gather + hist/binTot clear. Final pass: B1, B2, global scatter.
__global__ __launch_bounds__(1024) void order_radix_kernel(const float* __restrict__ x,
                                                           int* __restrict__ order) {
    const int b = blockIdx.x >> 1;
    const int v = blockIdx.x & 1;
    const int t = threadIdx.x;
    const int lane = t & 63;
    const int w = t >> 6;

    __shared__ uint32_t scode[NPTS];          // 16 KB
    __shared__ unsigned short sidx[NPTS];     // 8 KB
    __shared__ uint32_t hist[16 * 64];        // hist[d*64 + (w*4+r)], 4 KB
    __shared__ uint32_t binTot[16];
    __shared__ uint32_t baseArr[16];
    __shared__ float red[16 * 6];

    const float* xb = x + (size_t)b * NPTS * 3;

    // Load this thread's 4 elements (i = w*256 + r*64 + lane).
    float px[4], py[4], pz[4];
    #pragma unroll
    for (int r = 0; r < 4; ++r) {
        int i = (w << 8) + (r << 6) + lane;
        px[r] = xb[3*i+0]; py[r] = xb[3*i+1]; pz[r] = xb[3*i+2];
    }

    // Per-batch min/max reduction.
    float mnx = 1e30f, mny = 1e30f, mnz = 1e30f;
    float mxx = -1e30f, mxy = -1e30f, mxz = -1e30f;
    #pragma unroll
    for (int r = 0; r < 4; ++r) {
        mnx = fminf(mnx, px[r]); mxx = fmaxf(mxx, px[r]);
        mny = fminf(mny, py[r]); mxy = fmaxf(mxy, py[r]);
        mnz = fminf(mnz, pz[r]); mxz = fmaxf(mxz, pz[r]);
    }
    #pragma unroll
    for (int off = 32; off > 0; off >>= 1) {
        mnx = fminf(mnx, __shfl_xor(mnx, off));
        mny = fminf(mny, __shfl_xor(mny, off));
        mnz = fminf(mnz, __shfl_xor(mnz, off));
        mxx = fmaxf(mxx, __shfl_xor(mxx, off));
        mxy = fmaxf(mxy, __shfl_xor(mxy, off));
        mxz = fmaxf(mxz, __shfl_xor(mxz, off));
    }
    if (lane == 0) {
        red[w*6+0] = mnx; red[w*6+1] = mny; red[w*6+2] = mnz;
        red[w*6+3] = mxx; red[w*6+4] = mxy; red[w*6+5] = mxz;
    }
    // Clear hist/binTot while the reduction settles.
    hist[t & 1023] = 0u;      // 1024 entries, 1024 threads
    if (t < 16) binTot[t] = 0u;
    __syncthreads();
    if (t == 0) {
        for (int ww = 1; ww < 16; ++ww) {
            mnx = fminf(mnx, red[ww*6+0]); mny = fminf(mny, red[ww*6+1]);
            mnz = fminf(mnz, red[ww*6+2]); mxx = fmaxf(mxx, red[ww*6+3]);
            mxy = fmaxf(mxy, red[ww*6+4]); mxz = fmaxf(mxz, red[ww*6+5]);
        }
        red[0] = mnx; red[1] = mny; red[2] = mnz;
        red[3] = fmaxf(mxx - mnx, 1e-6f);
        red[4] = fmaxf(mxy - mny, 1e-6f);
        red[5] = fmaxf(mxz - mnz, 1e-6f);
    }
    __syncthreads();
    mnx = red[0]; mny = red[1]; mnz = red[2];
    const float spx = red[3], spy = red[4], spz = red[5];

    // Codes (24-bit) + idx payload.
    uint32_t code[4];
    unsigned short myidx[4];
    #pragma unroll
    for (int r = 0; r < 4; ++r) {
        int i = (w << 8) + (r << 6) + lane;
        float gx = fminf(fmaxf(((px[r] - mnx) / spx) * 255.0f, 0.0f), 255.0f);
        float gy = fminf(fmaxf(((py[r] - mny) / spy) * 255.0f, 0.0f), 255.0f);
        float gz = fminf(fmaxf(((pz[r] - mnz) / spz) * 255.0f, 0.0f), 255.0f);
        uint32_t ix = (uint32_t)(int)gx;
        uint32_t iy = (uint32_t)(int)gy;
        uint32_t iz = (uint32_t)(int)gz;
        uint32_t a0 = v ? iz : ix;
        uint32_t a2 = v ? ix : iz;
        code[r] = hilbert3(a0, iy, a2);
        myidx[r] = (unsigned short)i;
    }

    const u64 below_mask = (1ull << lane) - 1ull;
    int* ob = order + (((b << 1) | v) << 12);

    // 6 stable radix passes, 4-bit digits over code bits [0,24).
    #pragma unroll
    for (int p = 0; p < 6; ++p) {
        const int sh = 4 * p;

        // Rank within (wave, r) slot via ballot match; leaders publish slot
        // count and accumulate bin totals atomically (order-irrelevant).
        unsigned dd[4], rk[4];
        #pragma unroll
        for (int r = 0; r < 4; ++r) {
            unsigned d = (code[r] >> sh) & 15u;
            u64 m = ~0ull;
            #pragma unroll
            for (int bit = 0; bit < 4; ++bit) {
                u64 bal = __ballot((int)((d >> bit) & 1u));
                m &= ((d >> bit) & 1u) ? bal : ~bal;
            }
            unsigned rkr = (unsigned)__popcll(m & below_mask);
            dd[r] = d; rk[r] = rkr;
            if (rkr == 0u) {
                unsigned cnt = (unsigned)__popcll(m);
                hist[d * 64 + (w << 2) + r] = cnt;
                atomicAdd(&binTot[d], cnt);
            }
        }
        __syncthreads();   // B1

        // Wave w: exclusive scan of bin w's 64 slots. Wave 0 also scans binTot.
        {
            unsigned val = hist[w * 64 + lane];
            unsigned orig = val;
            #pragma unroll
            for (int off = 1; off < 64; off <<= 1) {
                unsigned nv = __shfl_up(val, off);
                if (lane >= off) val += nv;
            }
            hist[w * 64 + lane] = val - orig;
        }
        if (w == 0) {
            unsigned tv = (lane < 16) ? binTot[lane] : 0u;
            unsigned orig = tv;
            #pragma unroll
            for (int off = 1; off < 16; off <<= 1) {
                unsigned nv = __shfl_up(tv, off);
                if (lane >= off) tv += nv;
            }
            if (lane < 16) baseArr[lane] = tv - orig;
        }
        __syncthreads();   // B2

        unsigned pos[4];
        #pragma unroll
        for (int r = 0; r < 4; ++r)
            pos[r] = baseArr[dd[r]] + hist[dd[r] * 64 + (w << 2) + r] + rk[r];

        if (p < 5) {
            // Stable scatter through LDS, gather back, re-clear hist/binTot.
            #pragma unroll
            for (int r = 0; r < 4; ++r) {
                scode[pos[r]] = code[r];
                sidx[pos[r]] = myidx[r];
            }
            __syncthreads();   // B3
            #pragma unroll
            for (int r = 0; r < 4; ++r) {
                int i = (w << 8) + (r << 6) + lane;
                code[r] = scode[i];
                myidx[r] = sidx[i];
            }
            hist[t & 1023] = 0u;
            if (t < 16) binTot[t] = 0u;
            __syncthreads();   // B4
        } else {
            // Final pass: scatter indices straight to global.
            #pragma unroll
            for (int r = 0; r < 4; ++r)
                ob[pos[r]] = (int)myidx[r];
        }
    }
}

// Grid-stride over float4 output groups. Coeffs staged in LDS.
__global__ __launch_bounds__(256) void token_kernel(const float* __restrict__ x,
                                                    const float* __restrict__ W,
                                                    const float* __restrict__ bias,
                                                    const float* __restrict__ gamma,
                                                    const float* __restrict__ beta,
                                                    const int* __restrict__ order,
                                                    float* __restrict__ out) {
    __shared__ __align__(16) float sW0[2][DIM];
    __shared__ __align__(16) float sW1[2][DIM];
    __shared__ __align__(16) float sW2[2][DIM];
    __shared__ __align__(16) float sC[2][DIM];
    for (int i = threadIdx.x; i < 2 * DIM; i += 256) {
        int v = i / DIM;
        int d = i - v * DIM;
        float g = gamma[i];
        sW0[v][d] = g * W[d*3+0];
        sW1[v][d] = g * W[d*3+1];
        sW2[v][d] = g * W[d*3+2];
        sC[v][d]  = g * bias[d] + beta[i];
    }
    __syncthreads();

    const int total = BATCH * NTOK * F4PT;   // 12,582,912
    const int stride = gridDim.x * blockDim.x;
    for (int g4 = blockIdx.x * blockDim.x + threadIdx.x; g4 < total; g4 += stride) {
        int token = g4 / F4PT;
        int grp = g4 - token * F4PT;
        int b = token >> 13;           // / NTOK
        int nn = token & (NTOK - 1);
        int v = nn >> 12;              // / NPTS
        int n = nn & (NPTS - 1);
        int idx = order[(((b << 1) | v) << 12) + n];
        const float* p = x + (size_t)(b * NPTS + idx) * 3;
        float px = p[0], py = p[1], pz = p[2];
        int d0 = grp << 2;
        float4 w0 = *(const float4*)&sW0[v][d0];
        float4 w1 = *(const float4*)&sW1[v][d0];
        float4 w2 = *(const float4*)&sW2[v][d0];
        float4 c  = *(const float4*)&sC[v][d0];
        float4 o;
        o.x = px*w0.x + py*w1.x + pz*w2.x + c.x;
        o.y = px*w0.y + py*w1.y + pz*w2.y + c.y;
        o.z = px*w0.z + py*w1.z + pz*w2.z + c.z;
        o.w = px*w0.w + py*w1.w + pz*w2.w + c.w;
        reinterpret_cast<float4*>(out)[g4] = o;
    }
}

extern "C" void kernel_launch(void* const* d_in, const int* in_sizes, int n_in,
                              void* d_out, int out_size, void* d_ws, size_t ws_size,
                              hipStream_t stream) {
    const float* x     = (const float*)d_in[0];
    const float* W     = (const float*)d_in[1];
    const float* bias  = (const float*)d_in[2];
    const float* gamma = (const float*)d_in[3];
    const float* beta  = (const float*)d_in[4];

    int* order = (int*)d_ws;   // 16*2*4096 int32 = 512 KB

    hipLaunchKernelGGL(order_radix_kernel, dim3(BATCH * 2), dim3(1024), 0, stream, x, order);
    hipLaunchKernelGGL(token_kernel,       dim3(2048),      dim3(256),  0, stream,
                       x, W, bias, gamma, beta, order, (float*)d_out);
}

// Round 8
// 54.888 us; speedup vs baseline: 1.2144x; 1.1674x over previous
//
#include <hip/hip_runtime.h>
#include <stdint.h>

#define BATCH 16
#define NPTS 4096
#define DIM 384
#define NTOK (2*NPTS)
#define F4PT (DIM/4)   // 96 float4 groups per token

typedef unsigned long long u64;

// Morton spread: place bit b of an 8-bit value at position 3b.
__device__ __forceinline__ uint32_t spread3(uint32_t x) {
    x = (x | (x << 8)) & 0x00F00Fu;
    x = (x | (x << 4)) & 0x0C30C3u;
    x = (x | (x << 2)) & 0x249249u;
    return x;
}

// Exact port of the reference Skilling transform (bits=8, ndim=3).
__device__ __forceinline__ uint32_t hilbert3(uint32_t x0, uint32_t x1, uint32_t x2) {
    #pragma unroll
    for (uint32_t q = 128; q > 1; q >>= 1) {
        uint32_t pm = q - 1;
        if (x0 & q) x0 ^= pm;
        uint32_t t = (x0 ^ x1) & pm;
        if (x1 & q) { x0 ^= pm; } else { x0 ^= t; x1 ^= t; }
        t = (x0 ^ x2) & pm;
        if (x2 & q) { x0 ^= pm; } else { x0 ^= t; x2 ^= t; }
    }
    x1 ^= x0;
    x2 ^= x1;
    uint32_t t = 0;
    #pragma unroll
    for (uint32_t q = 128; q > 1; q >>= 1) { if (x2 & q) t ^= (q - 1); }
    x0 ^= t; x1 ^= t; x2 ^= t;
    return (spread3(x0) << 2) | (spread3(x1) << 1) | spread3(x2);
}

// K1: block = (b, v, quarter). 1024 threads, 1 element each. Computes batch
// minmax (redundant per block, L2-hot), codes its 1024 points, 6-pass 4-bit
// stable radix sort of the quarter, writes sorted keys to kws.
// Key = (code<<12)|global_idx -> all keys distinct.
__global__ __launch_bounds__(1024) void order_radix_q(const float* __restrict__ x,
                                                      u64* __restrict__ kws) {
    const int bi = blockIdx.x;
    const int b = bi >> 3;
    const int v = (bi >> 2) & 1;
    const int q = bi & 3;
    const int t = threadIdx.x;
    const int lane = t & 63;
    const int w = t >> 6;

    __shared__ u64 skey[1024];           // 8 KB
    __shared__ uint32_t hist[16 * 16];   // hist[d*16 + wave], 1 KB
    __shared__ uint32_t binTot[16];
    __shared__ uint32_t baseArr[16];
    __shared__ float red[16 * 6];

    const float* xb = x + (size_t)b * NPTS * 3;

    // Load 4 points (t + 1024g); the q-th is this thread's coding point.
    float px[4], py[4], pz[4];
    #pragma unroll
    for (int g = 0; g < 4; ++g) {
        int n = t + (g << 10);
        px[g] = xb[3*n+0]; py[g] = xb[3*n+1]; pz[g] = xb[3*n+2];
    }

    // Per-batch min/max reduction over all 4096 points.
    float mnx = 1e30f, mny = 1e30f, mnz = 1e30f;
    float mxx = -1e30f, mxy = -1e30f, mxz = -1e30f;
    #pragma unroll
    for (int g = 0; g < 4; ++g) {
        mnx = fminf(mnx, px[g]); mxx = fmaxf(mxx, px[g]);
        mny = fminf(mny, py[g]); mxy = fmaxf(mxy, py[g]);
        mnz = fminf(mnz, pz[g]); mxz = fmaxf(mxz, pz[g]);
    }
    #pragma unroll
    for (int off = 32; off > 0; off >>= 1) {
        mnx = fminf(mnx, __shfl_xor(mnx, off));
        mny = fminf(mny, __shfl_xor(mny, off));
        mnz = fminf(mnz, __shfl_xor(mnz, off));
        mxx = fmaxf(mxx, __shfl_xor(mxx, off));
        mxy = fmaxf(mxy, __shfl_xor(mxy, off));
        mxz = fmaxf(mxz, __shfl_xor(mxz, off));
    }
    if (lane == 0) {
        red[w*6+0] = mnx; red[w*6+1] = mny; red[w*6+2] = mnz;
        red[w*6+3] = mxx; red[w*6+4] = mxy; red[w*6+5] = mxz;
    }
    // Clear hist/binTot while the reduction settles.
    if (t < 256) hist[t] = 0u;
    if (t < 16) binTot[t] = 0u;
    __syncthreads();
    if (t == 0) {
        for (int ww = 1; ww < 16; ++ww) {
            mnx = fminf(mnx, red[ww*6+0]); mny = fminf(mny, red[ww*6+1]);
            mnz = fminf(mnz, red[ww*6+2]); mxx = fmaxf(mxx, red[ww*6+3]);
            mxy = fmaxf(mxy, red[ww*6+4]); mxz = fmaxf(mxz, red[ww*6+5]);
        }
        red[0] = mnx; red[1] = mny; red[2] = mnz;
        red[3] = fmaxf(mxx - mnx, 1e-6f);
        red[4] = fmaxf(mxy - mny, 1e-6f);
        red[5] = fmaxf(mxz - mnz, 1e-6f);
    }
    __syncthreads();
    mnx = red[0]; mny = red[1]; mnz = red[2];
    const float spx = red[3], spy = red[4], spz = red[5];

    // Code this thread's point n = q*1024 + t (its coords are slot q).
    u64 key;
    {
        int n = (q << 10) + t;
        float gx = fminf(fmaxf(((px[q] - mnx) / spx) * 255.0f, 0.0f), 255.0f);
        float gy = fminf(fmaxf(((py[q] - mny) / spy) * 255.0f, 0.0f), 255.0f);
        float gz = fminf(fmaxf(((pz[q] - mnz) / spz) * 255.0f, 0.0f), 255.0f);
        uint32_t ix = (uint32_t)(int)gx;
        uint32_t iy = (uint32_t)(int)gy;
        uint32_t iz = (uint32_t)(int)gz;
        uint32_t a0 = v ? iz : ix;
        uint32_t a2 = v ? ix : iz;
        uint32_t code = hilbert3(a0, iy, a2);
        key = ((u64)code << 12) | (u64)n;
    }

    const u64 below_mask = (1ull << lane) - 1ull;
    u64* segk = kws + (((b << 1) | v) << 12);

    // 6 stable radix passes, 4-bit digits over key bits [12, 36).
    #pragma unroll
    for (int p = 0; p < 6; ++p) {
        const int sh = 12 + 4 * p;

        unsigned d = (unsigned)(key >> sh) & 15u;
        u64 m = ~0ull;
        #pragma unroll
        for (int bit = 0; bit < 4; ++bit) {
            u64 bal = __ballot((int)((d >> bit) & 1u));
            m &= ((d >> bit) & 1u) ? bal : ~bal;
        }
        unsigned rk = (unsigned)__popcll(m & below_mask);
        if (rk == 0u) {
            unsigned cnt = (unsigned)__popcll(m);
            hist[d * 16 + w] = cnt;
            atomicAdd(&binTot[d], cnt);
        }
        __syncthreads();   // B1

        // Wave w: exclusive scan of bin w's 16 slots; wave 0 also scans binTot.
        {
            unsigned val = (lane < 16) ? hist[w * 16 + lane] : 0u;
            unsigned orig = val;
            #pragma unroll
            for (int off = 1; off < 16; off <<= 1) {
                unsigned nv = __shfl_up(val, off);
                if (lane >= off) val += nv;
            }
            if (lane < 16) hist[w * 16 + lane] = val - orig;
        }
        if (w == 0) {
            unsigned tv = (lane < 16) ? binTot[lane] : 0u;
            unsigned orig = tv;
            #pragma unroll
            for (int off = 1; off < 16; off <<= 1) {
                unsigned nv = __shfl_up(tv, off);
                if (lane >= off) tv += nv;
            }
            if (lane < 16) baseArr[lane] = tv - orig;
        }
        __syncthreads();   // B2

        unsigned pos = baseArr[d] + hist[d * 16 + w] + rk;

        if (p < 5) {
            skey[pos] = key;
            __syncthreads();   // B3
            key = skey[t];
            if (t < 256) hist[t] = 0u;
            if (t < 16) binTot[t] = 0u;
            __syncthreads();   // B4
        } else {
            // Final: write sorted quarter to global ws.
            segk[(q << 10) + pos] = key;
        }
    }
}

// K2: block = (b, v, quarter). Rank = own position + count-less in each of
// the other 3 sorted quarters (binary search in LDS). Keys distinct, so the
// result is exactly the stable argsort. Writes order[rank] = idx.
__global__ __launch_bounds__(1024) void order_merge_q(const u64* __restrict__ kws,
                                                      int* __restrict__ order) {
    const int bi = blockIdx.x;
    const int b = bi >> 3;
    const int v = (bi >> 2) & 1;
    const int q = bi & 3;
    const int t = threadIdx.x;

    __shared__ u64 sk[3][1024];   // 24 KB

    const u64* segk = kws + (((b << 1) | v) << 12);
    u64 k = segk[(q << 10) + t];

    #pragma unroll
    for (int j = 0; j < 3; ++j) {
        int oq = j + (j >= q ? 1 : 0);
        sk[j][t] = segk[(oq << 10) + t];
    }
    __syncthreads();

    int rank = t;
    #pragma unroll
    for (int j = 0; j < 3; ++j) {
        int c = 0;
        #pragma unroll
        for (int step = 1024; step >= 1; step >>= 1) {
            if (c + step <= 1024 && sk[j][c + step - 1] < k) c += step;
        }
        rank += c;
    }

    order[(((b << 1) | v) << 12) + rank] = (int)(k & 0xFFFull);
}

// Grid-stride over float4 output groups. Coeffs staged in LDS.
__global__ __launch_bounds__(256) void token_kernel(const float* __restrict__ x,
                                                    const float* __restrict__ W,
                                                    const float* __restrict__ bias,
                                                    const float* __restrict__ gamma,
                                                    const float* __restrict__ beta,
                                                    const int* __restrict__ order,
                                                    float* __restrict__ out) {
    __shared__ __align__(16) float sW0[2][DIM];
    __shared__ __align__(16) float sW1[2][DIM];
    __shared__ __align__(16) float sW2[2][DIM];
    __shared__ __align__(16) float sC[2][DIM];
    for (int i = threadIdx.x; i < 2 * DIM; i += 256) {
        int v = i / DIM;
        int d = i - v * DIM;
        float g = gamma[i];
        sW0[v][d] = g * W[d*3+0];
        sW1[v][d] = g * W[d*3+1];
        sW2[v][d] = g * W[d*3+2];
        sC[v][d]  = g * bias[d] + beta[i];
    }
    __syncthreads();

    const int total = BATCH * NTOK * F4PT;   // 12,582,912
    const int stride = gridDim.x * blockDim.x;
    for (int g4 = blockIdx.x * blockDim.x + threadIdx.x; g4 < total; g4 += stride) {
        int token = g4 / F4PT;
        int grp = g4 - token * F4PT;
        int b = token >> 13;           // / NTOK
        int nn = token & (NTOK - 1);
        int v = nn >> 12;              // / NPTS
        int n = nn & (NPTS - 1);
        int idx = order[(((b << 1) | v) << 12) + n];
        const float* p = x + (size_t)(b * NPTS + idx) * 3;
        float px = p[0], py = p[1], pz = p[2];
        int d0 = grp << 2;
        float4 w0 = *(const float4*)&sW0[v][d0];
        float4 w1 = *(const float4*)&sW1[v][d0];
        float4 w2 = *(const float4*)&sW2[v][d0];
        float4 c  = *(const float4*)&sC[v][d0];
        float4 o;
        o.x = px*w0.x + py*w1.x + pz*w2.x + c.x;
        o.y = px*w0.y + py*w1.y + pz*w2.y + c.y;
        o.z = px*w0.z + py*w1.z + pz*w2.z + c.z;
        o.w = px*w0.w + py*w1.w + pz*w2.w + c.w;
        reinterpret_cast<float4*>(out)[g4] = o;
    }
}

extern "C" void kernel_launch(void* const* d_in, const int* in_sizes, int n_in,
                              void* d_out, int out_size, void* d_ws, size_t ws_size,
                              hipStream_t stream) {
    const float* x     = (const float*)d_in[0];
    const float* W     = (const float*)d_in[1];
    const float* bias  = (const float*)d_in[2];
    const float* gamma = (const float*)d_in[3];
    const float* beta  = (const float*)d_in[4];

    u64* kws   = (u64*)d_ws;                    // 32*4096*8 = 1 MB
    int* order = (int*)(kws + 32 * 4096);       // 512 KB

    hipLaunchKernelGGL(order_radix_q, dim3(BATCH * 8), dim3(1024), 0, stream, x, kws);
    hipLaunchKernelGGL(order_merge_q, dim3(BATCH * 8), dim3(1024), 0, stream, kws, order);
    hipLaunchKernelGGL(token_kernel,  dim3(2048),      dim3(256),  0, stream,
                       x, W, bias, gamma, beta, order, (float*)d_out);
}

// Round 9
// 53.895 us; speedup vs baseline: 1.2368x; 1.0184x over previous
//
#include <hip/hip_runtime.h>
#include <stdint.h>

#define BATCH 16
#define NPTS 4096
#define DIM 384
#define NTOK (2*NPTS)
#define F4PT (DIM/4)   // 96 float4 groups per token

typedef unsigned long long u64;

// Morton spread: place bit b of an 8-bit value at position 3b.
__device__ __forceinline__ uint32_t spread3(uint32_t x) {
    x = (x | (x << 8)) & 0x00F00Fu;
    x = (x | (x << 4)) & 0x0C30C3u;
    x = (x | (x << 2)) & 0x249249u;
    return x;
}

// Exact port of the reference Skilling transform (bits=8, ndim=3).
__device__ __forceinline__ uint32_t hilbert3(uint32_t x0, uint32_t x1, uint32_t x2) {
    #pragma unroll
    for (uint32_t q = 128; q > 1; q >>= 1) {
        uint32_t pm = q - 1;
        if (x0 & q) x0 ^= pm;
        uint32_t t = (x0 ^ x1) & pm;
        if (x1 & q) { x0 ^= pm; } else { x0 ^= t; x1 ^= t; }
        t = (x0 ^ x2) & pm;
        if (x2 & q) { x0 ^= pm; } else { x0 ^= t; x2 ^= t; }
    }
    x1 ^= x0;
    x2 ^= x1;
    uint32_t t = 0;
    #pragma unroll
    for (uint32_t q = 128; q > 1; q >>= 1) { if (x2 & q) t ^= (q - 1); }
    x0 ^= t; x1 ^= t; x2 ^= t;
    return (spread3(x0) << 2) | (spread3(x1) << 1) | spread3(x2);
}

// K1: block = (b, v, octant). 512 threads, 1 element each. Batch minmax
// (vectorized, redundant per block, L2-hot), code own point, 6-pass 4-bit
// stable radix sort of the 512-element octant, write sorted run to kws.
// Key = (code<<12)|global_idx -> all keys distinct.
// Per pass: rank -> B1 -> scan -> B2 -> scatter -> B3. Per-pass hist regions
// are pre-zeroed once, so no re-clear barrier.
__global__ __launch_bounds__(512) void order_radix_o(const float* __restrict__ x,
                                                     u64* __restrict__ kws) {
    const int bi = blockIdx.x;
    const int b = bi >> 4;
    const int v = (bi >> 3) & 1;
    const int oct = bi & 7;
    const int t = threadIdx.x;
    const int lane = t & 63;
    const int w = t >> 6;          // 8 waves

    __shared__ u64 skey[512];             // 4 KB
    __shared__ uint32_t hist[6 * 128];    // per-pass regions hist[p][d*8+w], 3 KB
    __shared__ uint32_t baseArr[16];
    __shared__ float red[8 * 6];

    const float* xb = x + (size_t)b * NPTS * 3;
    const float4* xb4 = (const float4*)xb;

    // --- vectorized batch min/max: 8 points/thread (2 halves x 4 pts) ---
    float mnx = 1e30f, mny = 1e30f, mnz = 1e30f;
    float mxx = -1e30f, mxy = -1e30f, mxz = -1e30f;
    #pragma unroll
    for (int h = 0; h < 2; ++h) {
        float4 q0 = xb4[h * 1536 + 3 * t + 0];
        float4 q1 = xb4[h * 1536 + 3 * t + 1];
        float4 q2 = xb4[h * 1536 + 3 * t + 2];
        float px[4] = {q0.x, q0.w, q1.z, q2.y};
        float py[4] = {q0.y, q1.x, q1.w, q2.z};
        float pz[4] = {q0.z, q1.y, q2.x, q2.w};
        #pragma unroll
        for (int r = 0; r < 4; ++r) {
            mnx = fminf(mnx, px[r]); mxx = fmaxf(mxx, px[r]);
            mny = fminf(mny, py[r]); mxy = fmaxf(mxy, py[r]);
            mnz = fminf(mnz, pz[r]); mxz = fmaxf(mxz, pz[r]);
        }
    }
    #pragma unroll
    for (int off = 32; off > 0; off >>= 1) {
        mnx = fminf(mnx, __shfl_xor(mnx, off));
        mny = fminf(mny, __shfl_xor(mny, off));
        mnz = fminf(mnz, __shfl_xor(mnz, off));
        mxx = fmaxf(mxx, __shfl_xor(mxx, off));
        mxy = fmaxf(mxy, __shfl_xor(mxy, off));
        mxz = fmaxf(mxz, __shfl_xor(mxz, off));
    }
    if (lane == 0) {
        red[w*6+0] = mnx; red[w*6+1] = mny; red[w*6+2] = mnz;
        red[w*6+3] = mxx; red[w*6+4] = mxy; red[w*6+5] = mxz;
    }
    // Zero all per-pass hist regions while the reduction settles.
    hist[t] = 0u;                       // entries 0..511
    if (t < 256) hist[512 + t] = 0u;    // entries 512..767
    __syncthreads();
    if (t == 0) {
        for (int ww = 1; ww < 8; ++ww) {
            mnx = fminf(mnx, red[ww*6+0]); mny = fminf(mny, red[ww*6+1]);
            mnz = fminf(mnz, red[ww*6+2]); mxx = fmaxf(mxx, red[ww*6+3]);
            mxy = fmaxf(mxy, red[ww*6+4]); mxz = fmaxf(mxz, red[ww*6+5]);
        }
        red[0] = mnx; red[1] = mny; red[2] = mnz;
        red[3] = fmaxf(mxx - mnx, 1e-6f);
        red[4] = fmaxf(mxy - mny, 1e-6f);
        red[5] = fmaxf(mxz - mnz, 1e-6f);
    }
    __syncthreads();
    mnx = red[0]; mny = red[1]; mnz = red[2];
    const float spx = red[3], spy = red[4], spz = red[5];

    // Code own point n0 = oct*512 + t.
    u64 key;
    {
        const int n0 = (oct << 9) + t;
        float cx = xb[3*n0+0], cy = xb[3*n0+1], cz = xb[3*n0+2];
        float gx = fminf(fmaxf(((cx - mnx) / spx) * 255.0f, 0.0f), 255.0f);
        float gy = fminf(fmaxf(((cy - mny) / spy) * 255.0f, 0.0f), 255.0f);
        float gz = fminf(fmaxf(((cz - mnz) / spz) * 255.0f, 0.0f), 255.0f);
        uint32_t ix = (uint32_t)(int)gx;
        uint32_t iy = (uint32_t)(int)gy;
        uint32_t iz = (uint32_t)(int)gz;
        uint32_t a0 = v ? iz : ix;
        uint32_t a2 = v ? ix : iz;
        uint32_t code = hilbert3(a0, iy, a2);
        key = ((u64)code << 12) | (u64)n0;
    }

    const u64 below_mask = (1ull << lane) - 1ull;
    u64* segk = kws + (((b << 1) | v) << 12);

    // 6 stable radix passes, 4-bit digits over key bits [12, 36).
    #pragma unroll
    for (int p = 0; p < 6; ++p) {
        const int sh = 12 + 4 * p;
        uint32_t* histp = hist + p * 128;

        unsigned d = (unsigned)(key >> sh) & 15u;
        u64 m = ~0ull;
        #pragma unroll
        for (int bit = 0; bit < 4; ++bit) {
            u64 bal = __ballot((int)((d >> bit) & 1u));
            m &= ((d >> bit) & 1u) ? bal : ~bal;
        }
        unsigned rk = (unsigned)__popcll(m & below_mask);
        if (rk == 0u)
            histp[d * 8 + w] = (unsigned)__popcll(m);
        __syncthreads();   // B1

        // Threads 0..15 (wave 0): serial scan of bin t's 8 slots, then a
        // 16-lane shfl exclusive scan of bin totals -> baseArr.
        if (t < 16) {
            unsigned running = 0;
            #pragma unroll
            for (int s = 0; s < 8; ++s) {
                unsigned hv = histp[t * 8 + s];
                histp[t * 8 + s] = running;
                running += hv;
            }
            unsigned tv = running;
            #pragma unroll
            for (int off = 1; off < 16; off <<= 1) {
                unsigned nv = __shfl_up(tv, off);
                if (lane >= off) tv += nv;
            }
            baseArr[t] = tv - running;
        }
        __syncthreads();   // B2

        unsigned pos = baseArr[d] + histp[d * 8 + w] + rk;

        if (p < 5) {
            skey[pos] = key;
            __syncthreads();   // B3
            key = skey[t];
        } else {
            segk[(oct << 9) + pos] = key;
        }
    }
}

// K2: block = (b, v, octant). Rank = own position + count-less in each of the
// other 7 sorted runs (binary search in LDS). Keys distinct, so the result is
// exactly the stable argsort. Writes order[rank] = idx.
__global__ __launch_bounds__(512) void order_merge_o(const u64* __restrict__ kws,
                                                     int* __restrict__ order) {
    const int bi = blockIdx.x;
    const int b = bi >> 4;
    const int v = (bi >> 3) & 1;
    const int oct = bi & 7;
    const int t = threadIdx.x;

    __shared__ u64 sk[7 * 512];   // 28 KB

    const u64* segk = kws + (((b << 1) | v) << 12);
    u64 k = segk[(oct << 9) + t];

    #pragma unroll
    for (int j = 0; j < 7; ++j) {
        int oq = j + (j >= oct ? 1 : 0);
        sk[j * 512 + t] = segk[(oq << 9) + t];
    }
    __syncthreads();

    int rank = t;
    #pragma unroll
    for (int j = 0; j < 7; ++j) {
        const u64* s = &sk[j * 512];
        int c = 0;
        #pragma unroll
        for (int step = 512; step >= 1; step >>= 1) {
            if (c + step <= 512 && s[c + step - 1] < k) c += step;
        }
        rank += c;
    }

    order[(((b << 1) | v) << 12) + rank] = (int)(k & 0xFFFull);
}

// Grid-stride over float4 output groups. Coeffs staged in LDS.
__global__ __launch_bounds__(256) void token_kernel(const float* __restrict__ x,
                                                    const float* __restrict__ W,
                                                    const float* __restrict__ bias,
                                                    const float* __restrict__ gamma,
                                                    const float* __restrict__ beta,
                                                    const int* __restrict__ order,
                                                    float* __restrict__ out) {
    __shared__ __align__(16) float sW0[2][DIM];
    __shared__ __align__(16) float sW1[2][DIM];
    __shared__ __align__(16) float sW2[2][DIM];
    __shared__ __align__(16) float sC[2][DIM];
    for (int i = threadIdx.x; i < 2 * DIM; i += 256) {
        int v = i / DIM;
        int d = i - v * DIM;
        float g = gamma[i];
        sW0[v][d] = g * W[d*3+0];
        sW1[v][d] = g * W[d*3+1];
        sW2[v][d] = g * W[d*3+2];
        sC[v][d]  = g * bias[d] + beta[i];
    }
    __syncthreads();

    const int total = BATCH * NTOK * F4PT;   // 12,582,912
    const int stride = gridDim.x * blockDim.x;
    for (int g4 = blockIdx.x * blockDim.x + threadIdx.x; g4 < total; g4 += stride) {
        int token = g4 / F4PT;
        int grp = g4 - token * F4PT;
        int b = token >> 13;           // / NTOK
        int nn = token & (NTOK - 1);
        int v = nn >> 12;              // / NPTS
        int n = nn & (NPTS - 1);
        int idx = order[(((b << 1) | v) << 12) + n];
        const float* p = x + (size_t)(b * NPTS + idx) * 3;
        float px = p[0], py = p[1], pz = p[2];
        int d0 = grp << 2;
        float4 w0 = *(const float4*)&sW0[v][d0];
        float4 w1 = *(const float4*)&sW1[v][d0];
        float4 w2 = *(const float4*)&sW2[v][d0];
        float4 c  = *(const float4*)&sC[v][d0];
        float4 o;
        o.x = px*w0.x + py*w1.x + pz*w2.x + c.x;
        o.y = px*w0.y + py*w1.y + pz*w2.y + c.y;
        o.z = px*w0.z + py*w1.z + pz*w2.z + c.z;
        o.w = px*w0.w + py*w1.w + pz*w2.w + c.w;
        reinterpret_cast<float4*>(out)[g4] = o;
    }
}

extern "C" void kernel_launch(void* const* d_in, const int* in_sizes, int n_in,
                              void* d_out, int out_size, void* d_ws, size_t ws_size,
                              hipStream_t stream) {
    const float* x     = (const float*)d_in[0];
    const float* W     = (const float*)d_in[1];
    const float* bias  = (const float*)d_in[2];
    const float* gamma = (const float*)d_in[3];
    const float* beta  = (const float*)d_in[4];

    u64* kws   = (u64*)d_ws;                    // 32*4096*8 = 1 MB
    int* order = (int*)(kws + 32 * 4096);       // 512 KB

    hipLaunchKernelGGL(order_radix_o, dim3(BATCH * 16), dim3(512), 0, stream, x, kws);
    hipLaunchKernelGGL(order_merge_o, dim3(BATCH * 16), dim3(512), 0, stream, kws, order);
    hipLaunchKernelGGL(token_kernel,  dim3(2048),       dim3(256), 0, stream,
                       x, W, bias, gamma, beta, order, (float*)d_out);
}